// Round 1
// baseline (376.983 us; speedup 1.0000x reference)
//
#include <hip/hip_runtime.h>

#define BB 16
#define NN 32
#define HH 480
#define WW 480
#define HW (HH * WW)        // 230400
#define HW4 (HW / 4)        // 57600

__device__ __forceinline__ float block_reduce_sum(float acc) {
    // wave64 butterfly reduce
    #pragma unroll
    for (int off = 32; off; off >>= 1) acc += __shfl_xor(acc, off, 64);
    __shared__ float s[8];
    int lane = threadIdx.x & 63;
    int wid  = threadIdx.x >> 6;
    if (lane == 0) s[wid] = acc;
    __syncthreads();
    float r = 0.f;
    if (threadIdx.x == 0) {
        int nw = (blockDim.x + 63) >> 6;
        for (int i = 0; i < nw; ++i) r += s[i];
    }
    return r;  // valid on thread 0 only
}

// K1: per-batch target area -> ws[b]
__global__ void tgt_area_kernel(const float* __restrict__ tgt, float* __restrict__ ws) {
    int b = blockIdx.x;
    const float4* t4 = (const float4*)(tgt + (size_t)b * HW);
    float acc = 0.f;
    for (int i = threadIdx.x; i < HW4; i += blockDim.x) {
        float4 t = t4[i];
        acc += t.x + t.y + t.z + t.w;
    }
    float r = block_reduce_sum(acc);
    if (threadIdx.x == 0) ws[b] = r;
}

// K2: overlap[b,n] = sum(obj[b,n]*tgt[b]) -> out[bn*2+0]
__global__ void overlap_kernel(const float* __restrict__ tgt,
                               const float* __restrict__ obj,
                               float* __restrict__ out) {
    int bn = blockIdx.x;            // b*NN + n
    int b  = bn / NN;
    const float4* o4 = (const float4*)(obj + (size_t)bn * HW);
    const float4* t4 = (const float4*)(tgt + (size_t)b * HW);
    float acc = 0.f;
    for (int i = threadIdx.x; i < HW4; i += blockDim.x) {
        float4 a = o4[i];
        float4 t = t4[i];
        acc += a.x * t.x + a.y * t.y + a.z * t.z + a.w * t.w;
    }
    float r = block_reduce_sum(acc);
    if (threadIdx.x == 0) out[bn * 2 + 0] = r;
}

// K3: iou[b,n] -> out[bn*2+1]
__global__ void iou_kernel(const float* __restrict__ tgt,
                           const int* __restrict__ bbox,
                           const float* __restrict__ ws,
                           float* __restrict__ out) {
    int bn = blockIdx.x;
    int b  = bn / NN;
    int x1 = bbox[bn * 4 + 0];
    int y1 = bbox[bn * 4 + 1];
    int x2 = bbox[bn * 4 + 2];
    int y2 = bbox[bn * 4 + 3];
    int bw = x2 > x1 ? (x2 - x1) : 0;
    int bh = y2 > y1 ? (y2 - y1) : 0;
    long total = (long)bw * (long)bh;
    const float* t = tgt + (size_t)b * HW;
    float acc = 0.f;
    for (long i = threadIdx.x; i < total; i += blockDim.x) {
        int y = y1 + (int)(i / bw);
        int x = x1 + (int)(i % bw);
        acc += t[y * WW + x];
    }
    float inter = block_reduce_sum(acc);
    if (threadIdx.x == 0) {
        float area = (float)(bw * bh);
        float uni  = area + ws[b] - inter;
        out[bn * 2 + 1] = inter / (uni + 1e-8f);
    }
}

extern "C" void kernel_launch(void* const* d_in, const int* in_sizes, int n_in,
                              void* d_out, int out_size, void* d_ws, size_t ws_size,
                              hipStream_t stream) {
    const float* tgt  = (const float*)d_in[0];   // (B,H,W)
    const float* obj  = (const float*)d_in[1];   // (B,N,H,W)
    const int*   bbox = (const int*)d_in[2];     // (B,N,4)
    float* out = (float*)d_out;                  // (B,N,2)
    float* ws  = (float*)d_ws;                   // >= 16 floats

    tgt_area_kernel<<<BB, 256, 0, stream>>>(tgt, ws);
    overlap_kernel<<<BB * NN, 256, 0, stream>>>(tgt, obj, out);
    iou_kernel<<<BB * NN, 256, 0, stream>>>(tgt, bbox, ws, out);
}

// Round 2
// 264.805 us; speedup vs baseline: 1.4236x; 1.4236x over previous
//
#include <hip/hip_runtime.h>

#define BB 16
#define NN 32
#define HH 480
#define WW 480
#define HW (HH * WW)        // 230400
#define HW4 (HW / 4)        // 57600

template <int NWAVES>
__device__ __forceinline__ float block_reduce_sum(float acc) {
    // wave64 butterfly reduce
    #pragma unroll
    for (int off = 32; off; off >>= 1) acc += __shfl_xor(acc, off, 64);
    __shared__ float s[NWAVES];
    int lane = threadIdx.x & 63;
    int wid  = threadIdx.x >> 6;
    if (lane == 0) s[wid] = acc;
    __syncthreads();
    float r = 0.f;
    if (threadIdx.x == 0) {
        #pragma unroll
        for (int i = 0; i < NWAVES; ++i) r += s[i];
    }
    return r;  // valid on thread 0 only
}

// K1: per-batch target area -> ws[b]
__global__ __launch_bounds__(1024) void tgt_area_kernel(const float* __restrict__ tgt,
                                                        float* __restrict__ ws) {
    int b = blockIdx.x;
    const float4* t4 = (const float4*)(tgt + (size_t)b * HW);
    float acc = 0.f;
    for (int i = threadIdx.x; i < HW4; i += 1024) {
        float4 t = t4[i];
        acc += (t.x + t.y) + (t.z + t.w);
    }
    float r = block_reduce_sum<16>(acc);
    if (threadIdx.x == 0) ws[b] = r;
}

// K2: overlap[b,n] = sum(obj[b,n]*tgt[b]) -> out[bn*2+0]
// 1024 threads/block, 512 blocks -> 2 blocks/CU, 8 waves/SIMD (full occupancy).
// Manual 4-way unroll: 8 independent float4 loads in flight per thread.
__global__ __launch_bounds__(1024) void overlap_kernel(const float* __restrict__ tgt,
                                                       const float* __restrict__ obj,
                                                       float* __restrict__ out) {
    int bn = blockIdx.x;            // b*NN + n
    int b  = bn >> 5;
    const float4* o4 = (const float4*)(obj + (size_t)bn * HW);
    const float4* t4 = (const float4*)(tgt + (size_t)b * HW);

    float a0 = 0.f, a1 = 0.f, a2 = 0.f, a3 = 0.f;
    int i = threadIdx.x;
    // HW4 = 57600 = 56*1024 + 256; 56/4 = 14 full unrolled iterations.
    #pragma unroll 2
    for (; i + 3 * 1024 < HW4; i += 4 * 1024) {
        float4 o0 = o4[i];
        float4 o1 = o4[i + 1024];
        float4 o2 = o4[i + 2048];
        float4 o3 = o4[i + 3072];
        float4 t0 = t4[i];
        float4 t1 = t4[i + 1024];
        float4 t2 = t4[i + 2048];
        float4 t3 = t4[i + 3072];
        a0 += o0.x * t0.x + o0.y * t0.y + o0.z * t0.z + o0.w * t0.w;
        a1 += o1.x * t1.x + o1.y * t1.y + o1.z * t1.z + o1.w * t1.w;
        a2 += o2.x * t2.x + o2.y * t2.y + o2.z * t2.z + o2.w * t2.w;
        a3 += o3.x * t3.x + o3.y * t3.y + o3.z * t3.z + o3.w * t3.w;
    }
    for (; i < HW4; i += 1024) {
        float4 o = o4[i];
        float4 t = t4[i];
        a0 += o.x * t.x + o.y * t.y + o.z * t.z + o.w * t.w;
    }
    float acc = (a0 + a1) + (a2 + a3);
    float r = block_reduce_sum<16>(acc);
    if (threadIdx.x == 0) out[bn * 2 + 0] = r;
}

// K3: iou[b,n] -> out[bn*2+1]
// 2D tiling: 4 rows x 64 cols per step; no integer divides, coalesced rows.
__global__ __launch_bounds__(256) void iou_kernel(const float* __restrict__ tgt,
                                                  const int* __restrict__ bbox,
                                                  const float* __restrict__ ws,
                                                  float* __restrict__ out) {
    int bn = blockIdx.x;
    int b  = bn >> 5;
    int x1 = bbox[bn * 4 + 0];
    int y1 = bbox[bn * 4 + 1];
    int x2 = bbox[bn * 4 + 2];
    int y2 = bbox[bn * 4 + 3];
    int bw = x2 > x1 ? (x2 - x1) : 0;
    int bh = y2 > y1 ? (y2 - y1) : 0;

    const float* t = tgt + (size_t)b * HW;
    int tx = threadIdx.x & 63;
    int ty = threadIdx.x >> 6;     // 0..3
    float acc = 0.f;
    if (bw > 0 && bh > 0) {
        for (int y = y1 + ty; y < y2; y += 4) {
            const float* row = t + y * WW;
            for (int x = x1 + tx; x < x2; x += 64) acc += row[x];
        }
    }
    float inter = block_reduce_sum<4>(acc);
    if (threadIdx.x == 0) {
        float area = (float)(bw * bh);
        float uni  = area + ws[b] - inter;
        out[bn * 2 + 1] = inter / (uni + 1e-8f);
    }
}

extern "C" void kernel_launch(void* const* d_in, const int* in_sizes, int n_in,
                              void* d_out, int out_size, void* d_ws, size_t ws_size,
                              hipStream_t stream) {
    const float* tgt  = (const float*)d_in[0];   // (B,H,W)
    const float* obj  = (const float*)d_in[1];   // (B,N,H,W)
    const int*   bbox = (const int*)d_in[2];     // (B,N,4)
    float* out = (float*)d_out;                  // (B,N,2)
    float* ws  = (float*)d_ws;                   // >= 16 floats

    tgt_area_kernel<<<BB, 1024, 0, stream>>>(tgt, ws);
    iou_kernel<<<BB * NN, 256, 0, stream>>>(tgt, bbox, ws, out);
    overlap_kernel<<<BB * NN, 1024, 0, stream>>>(tgt, obj, out);
}

// Round 4
// 87.147 us; speedup vs baseline: 4.3258x; 3.0386x over previous
//
#include <hip/hip_runtime.h>

#define BB 16
#define NN 32
#define HH 480
#define WW 480
#define HW (HH * WW)          // 230400
#define HW4 (HW / 4)          // 57600 float4 per (b,n) image
#define SLICES 8
#define SL4 (HW4 / SLICES)    // 7200 float4 per slice
#define W4 (WW / 4)           // 120 float4 per row

typedef float vf4 __attribute__((ext_vector_type(4)));   // native vector: ok for nontemporal builtins

// Fused pass: for each (b,n) slice, accumulate
//   ov  = sum(obj * tgt)            (overlap partial)
//   it  = sum(tgt inside bbox)      (intersection partial)
//   ar  = sum(tgt)                  (tgt-area partial)
// obj is streamed with nontemporal loads (nt -> no L2/L3 allocate) so the
// 32x-reused tgt stays cache-resident.
__global__ __launch_bounds__(256) void fused_kernel(const float* __restrict__ tgt,
                                                    const float* __restrict__ obj,
                                                    const int* __restrict__ bbox,
                                                    float* __restrict__ ws) {
    int blk = blockIdx.x;       // 0 .. BB*NN*SLICES-1
    int bn  = blk >> 3;
    int s   = blk & (SLICES - 1);
    int b   = bn >> 5;

    int x1 = bbox[bn * 4 + 0];
    int y1 = bbox[bn * 4 + 1];
    int x2 = bbox[bn * 4 + 2];
    int y2 = bbox[bn * 4 + 3];

    const vf4* o4 = (const vf4*)(obj + (size_t)bn * HW);
    const vf4* t4 = (const vf4*)(tgt + (size_t)b * HW);

    float ov = 0.f, it = 0.f, ar = 0.f;
    int i0 = s * SL4;
    #pragma unroll 4
    for (int i = i0 + threadIdx.x; i < i0 + SL4; i += 256) {
        vf4 o = __builtin_nontemporal_load(&o4[i]);
        vf4 t = t4[i];
        ov += o.x * t.x + o.y * t.y + o.z * t.z + o.w * t.w;
        ar += (t.x + t.y) + (t.z + t.w);
        int y  = i / W4;              // const-div -> mulhi
        int x0 = (i - y * W4) * 4;    // 4 consecutive x, same y
        float iny = (y >= y1 && y < y2) ? 1.f : 0.f;
        float c0 = (x0 + 0 >= x1 && x0 + 0 < x2) ? t.x : 0.f;
        float c1 = (x0 + 1 >= x1 && x0 + 1 < x2) ? t.y : 0.f;
        float c2 = (x0 + 2 >= x1 && x0 + 2 < x2) ? t.z : 0.f;
        float c3 = (x0 + 3 >= x1 && x0 + 3 < x2) ? t.w : 0.f;
        it += iny * ((c0 + c1) + (c2 + c3));
    }

    // block reduce 3 values (4 waves)
    #pragma unroll
    for (int off = 32; off; off >>= 1) {
        ov += __shfl_xor(ov, off, 64);
        it += __shfl_xor(it, off, 64);
        ar += __shfl_xor(ar, off, 64);
    }
    __shared__ float sm[3][4];
    int lane = threadIdx.x & 63;
    int wid  = threadIdx.x >> 6;
    if (lane == 0) { sm[0][wid] = ov; sm[1][wid] = it; sm[2][wid] = ar; }
    __syncthreads();
    if (threadIdx.x == 0) {
        float rov = (sm[0][0] + sm[0][1]) + (sm[0][2] + sm[0][3]);
        float rit = (sm[1][0] + sm[1][1]) + (sm[1][2] + sm[1][3]);
        float rar = (sm[2][0] + sm[2][1]) + (sm[2][2] + sm[2][3]);
        float4 w = make_float4(rov, rit, rar, 0.f);
        ((float4*)ws)[blk] = w;
    }
}

// Combine the 8 slice-partials per (b,n) and write both edge features.
__global__ __launch_bounds__(256) void finish_kernel(const int* __restrict__ bbox,
                                                     const float* __restrict__ ws,
                                                     float* __restrict__ out) {
    int bn = blockIdx.x * 256 + threadIdx.x;
    if (bn >= BB * NN) return;
    float ov = 0.f, it = 0.f, ar = 0.f;
    #pragma unroll
    for (int s = 0; s < SLICES; ++s) {
        float4 w = ((const float4*)ws)[bn * SLICES + s];
        ov += w.x; it += w.y; ar += w.z;
    }
    int x1 = bbox[bn * 4 + 0];
    int y1 = bbox[bn * 4 + 1];
    int x2 = bbox[bn * 4 + 2];
    int y2 = bbox[bn * 4 + 3];
    int bw = x2 > x1 ? (x2 - x1) : 0;
    int bh = y2 > y1 ? (y2 - y1) : 0;
    float area = (float)bw * (float)bh;
    float uni  = area + ar - it;
    out[bn * 2 + 0] = ov;
    out[bn * 2 + 1] = it / (uni + 1e-8f);
}

extern "C" void kernel_launch(void* const* d_in, const int* in_sizes, int n_in,
                              void* d_out, int out_size, void* d_ws, size_t ws_size,
                              hipStream_t stream) {
    const float* tgt  = (const float*)d_in[0];   // (B,H,W)
    const float* obj  = (const float*)d_in[1];   // (B,N,H,W)
    const int*   bbox = (const int*)d_in[2];     // (B,N,4)
    float* out = (float*)d_out;                  // (B,N,2)
    float* ws  = (float*)d_ws;                   // needs BB*NN*SLICES*4 floats = 64 KiB

    fused_kernel<<<BB * NN * SLICES, 256, 0, stream>>>(tgt, obj, bbox, ws);
    finish_kernel<<<2, 256, 0, stream>>>(bbox, ws, out);
}